// Round 12
// baseline (56.058 us; speedup 1.0000x reference)
//
#include <hip/hip_runtime.h>
#include <hip/hip_bf16.h>

typedef __attribute__((ext_vector_type(8))) short bf16x8;
typedef __attribute__((ext_vector_type(4))) float f32x4;

__device__ __forceinline__ short f2bf(float x) {
    __hip_bfloat16 t = __float2bfloat16(x);
    return __builtin_bit_cast(short, t);
}

// B=16, N=4096, K=16, hidden=64, dim=64
// R12 = R10 (50.5us champion: NT/plain 2MB stripe) with ONE change:
// occupancy 12 -> 4 waves/CU (grid 256 blocks, 1 blk/CU, stride 1024,
// 64 iters/wave). Tests whether thousands of concurrent 4KB write-stream
// fronts degrade DRAM write locality; the 6.9 TB/s fill kernel runs at
// ~3 waves/CU. Also makes per-wave work perfectly uniform (no tail).

__global__ __launch_bounds__(256, 1) void ppe_kernel(
    const float* __restrict__ xyz,   // [16,4096,3]
    const float* __restrict__ dist,  // [16,4096,16]
    const float* __restrict__ W1,    // [10,64]
    const float* __restrict__ b1,    // [64]
    const float* __restrict__ W2,    // [64,64]
    const float* __restrict__ b2,    // [64]
    const int*   __restrict__ idx,   // [16,4096,16] (int32)
    float* __restrict__ out)         // [16,4096,16,64]
{
    __shared__ float sbuf[4][1024];  // 4 KB per wave, wave-private

    const int lane = threadIdx.x & 63;
    const int warp = threadIdx.x >> 6;
    const int wid  = (blockIdx.x * blockDim.x + threadIdx.x) >> 6; // 0..1023
    const int u    = lane >> 4;   // 0..3
    const int p    = lane & 15;   // 0..15

    float* const ws = &sbuf[warp][0];

    // ---- persistent weight fragments (identical to R5) ----
    bf16x8 w1f[4];
#pragma unroll
    for (int t = 0; t < 4; ++t) {
        const int hu = 16 * t + p;
#pragma unroll
        for (int j = 0; j < 8; ++j) {
            float coef;
            if (j < 3)      coef = W1[j * 64 + hu] + W1[(6 + j) * 64 + hu];
            else if (j < 6) coef = W1[j * 64 + hu] - W1[(j + 3) * 64 + hu];
            else if (j == 6) coef = W1[9 * 64 + hu];
            else             coef = b1[hu];
            w1f[t][j] = (u == 0) ? f2bf(coef) : (short)0;
        }
    }

    bf16x8 w2f[4][2];
#pragma unroll
    for (int dt = 0; dt < 4; ++dt)
#pragma unroll
        for (int kt = 0; kt < 2; ++kt)
#pragma unroll
            for (int j = 0; j < 8; ++j) {
                const int unit = 32 * kt + 16 * (j >> 2) + 4 * u + (j & 3);
                w2f[dt][kt][j] = f2bf(W2[unit * 64 + 16 * dt + p]);
            }

    float b2r[4][4];
#pragma unroll
    for (int dt = 0; dt < 4; ++dt)
#pragma unroll
        for (int r = 0; r < 4; ++r)
            b2r[dt][r] = b2[16 * dt + 4 * u + r];

    const short one_bf = f2bf(1.0f);
    const int NG = 65536, S = 1024;

    // ---- software-pipeline prologue ----
    const int g0 = wid;
    const int row0 = g0 * 16 + p;
    int   nb0 = idx[row0];
    float dC  = dist[row0];
    const float* cp0 = xyz + (size_t)g0 * 3;
    float cC0 = cp0[0], cC1 = cp0[1], cC2 = cp0[2];
    const float* np0 = xyz + ((size_t)((g0 >> 12) * 4096) + nb0) * 3;
    float nC0 = np0[0], nC1 = np0[1], nC2 = np0[2];
    const int row1 = (g0 + S) * 16 + p;
    int   nbN = idx[row1];
    float dN  = dist[row1];

    for (int g = g0; g < NG; g += S) {
        int gB = g + S;     if (gB >= NG) gB = g;   // t+1 (clamped dummy)
        int gA = g + 2 * S; if (gA >= NG) gA = g;   // t+2 (clamped dummy)

        // ---- 1. issue xyz loads for t+1 (neighbor addr from resident nbN) ----
        const float* cpn = xyz + (size_t)gB * 3;
        float cL0 = cpn[0], cL1 = cpn[1], cL2 = cpn[2];
        const float* npn = xyz + ((size_t)((gB >> 12) * 4096) + nbN) * 3;
        float nL0 = npn[0], nL1 = npn[1], nL2 = npn[2];

        // ---- 2. issue idx/dist loads for t+2 ----
        const int rowA = gA * 16 + p;
        int   nbL = idx[rowA];
        float dL  = dist[rowA];

        // ---- 3. layer-1 MFMA ----
        bf16x8 fa;
        fa[0] = f2bf(cC0); fa[1] = f2bf(cC1); fa[2] = f2bf(cC2);
        fa[3] = f2bf(nC0); fa[4] = f2bf(nC1); fa[5] = f2bf(nC2);
        fa[6] = f2bf(dC);  fa[7] = one_bf;

        f32x4 acc1[4];
#pragma unroll
        for (int t = 0; t < 4; ++t) {
            acc1[t] = (f32x4){0.f, 0.f, 0.f, 0.f};
            acc1[t] = __builtin_amdgcn_mfma_f32_16x16x32_bf16(w1f[t], fa, acc1[t], 0, 0, 0);
            acc1[t][0] = fmaxf(acc1[t][0], 0.f);
            acc1[t][1] = fmaxf(acc1[t][1], 0.f);
            acc1[t][2] = fmaxf(acc1[t][2], 0.f);
            acc1[t][3] = fmaxf(acc1[t][3], 0.f);
        }

        // ---- 4. layer-2 B-frag directly from acc1 (permutation-matched) ----
        bf16x8 hb[2];
#pragma unroll
        for (int kt = 0; kt < 2; ++kt)
#pragma unroll
            for (int j = 0; j < 8; ++j)
                hb[kt][j] = f2bf(acc1[2 * kt + (j >> 2)][j & 3]);

        // ---- 5. layer-2 MFMA, bias in C-init: D2[dim][pt] ----
        f32x4 acc2[4];
#pragma unroll
        for (int dt = 0; dt < 4; ++dt) {
            acc2[dt] = (f32x4){b2r[dt][0], b2r[dt][1], b2r[dt][2], b2r[dt][3]};
            acc2[dt] = __builtin_amdgcn_mfma_f32_16x16x32_bf16(w2f[dt][0], hb[0], acc2[dt], 0, 0, 0);
            acc2[dt] = __builtin_amdgcn_mfma_f32_16x16x32_bf16(w2f[dt][1], hb[1], acc2[dt], 0, 0, 0);
        }

        // ---- 6. transpose via LDS (swizzled, conflict-free) ----
#pragma unroll
        for (int dt = 0; dt < 4; ++dt) {
            const int col = (16 * dt + 4 * u) ^ ((p & 1) << 4);
            *(f32x4*)&ws[p * 64 + col] = acc2[dt];
        }

        // ---- 7. LDS -> 4x 1KB contiguous stores; NT/plain striped at 2MB ----
        float* const obase = out + (size_t)g * 1024;
        if ((g >> 9) & 1) {
#pragma unroll
            for (int i = 0; i < 4; ++i) {
                const int pt = 4 * i + u;
                f32x4 v = *(const f32x4*)&ws[pt * 64 + ((4 * p) ^ ((u & 1) << 4))];
                __builtin_nontemporal_store(v, (f32x4*)&obase[i * 256 + lane * 4]);
            }
        } else {
#pragma unroll
            for (int i = 0; i < 4; ++i) {
                const int pt = 4 * i + u;
                f32x4 v = *(const f32x4*)&ws[pt * 64 + ((4 * p) ^ ((u & 1) << 4))];
                *(f32x4*)&obase[i * 256 + lane * 4] = v;
            }
        }

        // ---- 8. rotate pipeline registers ----
        cC0 = cL0; cC1 = cL1; cC2 = cL2;
        nC0 = nL0; nC1 = nL1; nC2 = nL2;
        dC  = dN;  dN  = dL;  nbN = nbL;
    }
}

extern "C" void kernel_launch(void* const* d_in, const int* in_sizes, int n_in,
                              void* d_out, int out_size, void* d_ws, size_t ws_size,
                              hipStream_t stream) {
    const float* xyz  = (const float*)d_in[0];
    const float* dist = (const float*)d_in[1];
    const float* W1   = (const float*)d_in[2];
    const float* b1   = (const float*)d_in[3];
    const float* W2   = (const float*)d_in[4];
    const float* b2   = (const float*)d_in[5];
    const int*   idx  = (const int*)d_in[6];
    float* out = (float*)d_out;

    ppe_kernel<<<dim3(256), dim3(256), 0, stream>>>(xyz, dist, W1, b1, W2, b2, idx, out);
}

// Round 13
// 50.222 us; speedup vs baseline: 1.1162x; 1.1162x over previous
//
#include <hip/hip_runtime.h>
#include <hip/hip_bf16.h>

typedef __attribute__((ext_vector_type(8))) short bf16x8;
typedef __attribute__((ext_vector_type(4))) float f32x4;

__device__ __forceinline__ short f2bf(float x) {
    __hip_bfloat16 t = __float2bfloat16(x);
    return __builtin_bit_cast(short, t);
}

// B=16, N=4096, K=16, hidden=64, dim=64
// R13 = R10 (50.5us champion: NT/plain 2MB stripe, 768 blocks, 12 w/CU)
// with ONE change: XCD-aware block swizzle bid -> (bid&7)*96 + bid>>3.
// With round-robin block->XCD dispatch, each XCD now owns a CONTIGUOUS
// 384-group (1.5MB) run per iteration of the collective 12MB write window,
// instead of 16KB fragments strided by 128KB. Tests per-XCD write-run
// locality (writeback / NT-stream merge) -- the last unswept axis.

__global__ __launch_bounds__(256, 3) void ppe_kernel(
    const float* __restrict__ xyz,   // [16,4096,3]
    const float* __restrict__ dist,  // [16,4096,16]
    const float* __restrict__ W1,    // [10,64]
    const float* __restrict__ b1,    // [64]
    const float* __restrict__ W2,    // [64,64]
    const float* __restrict__ b2,    // [64]
    const int*   __restrict__ idx,   // [16,4096,16] (int32)
    float* __restrict__ out)         // [16,4096,16,64]
{
    __shared__ float sbuf[4][1024];  // 4 KB per wave, wave-private

    const int lane = threadIdx.x & 63;
    const int warp = threadIdx.x >> 6;
    // XCD-aware swizzle: 768 blocks = 8 XCDs x 96. Round-robin dispatch
    // puts bid%8 on XCD (bid&7); give that XCD the contiguous chunk.
    const int bswz = (blockIdx.x & 7) * 96 + (blockIdx.x >> 3);
    const int wid  = bswz * 4 + warp;            // 0..3071
    const int u    = lane >> 4;   // 0..3
    const int p    = lane & 15;   // 0..15

    float* const ws = &sbuf[warp][0];

    // ---- persistent weight fragments (identical to R5) ----
    bf16x8 w1f[4];
#pragma unroll
    for (int t = 0; t < 4; ++t) {
        const int hu = 16 * t + p;
#pragma unroll
        for (int j = 0; j < 8; ++j) {
            float coef;
            if (j < 3)      coef = W1[j * 64 + hu] + W1[(6 + j) * 64 + hu];
            else if (j < 6) coef = W1[j * 64 + hu] - W1[(j + 3) * 64 + hu];
            else if (j == 6) coef = W1[9 * 64 + hu];
            else             coef = b1[hu];
            w1f[t][j] = (u == 0) ? f2bf(coef) : (short)0;
        }
    }

    bf16x8 w2f[4][2];
#pragma unroll
    for (int dt = 0; dt < 4; ++dt)
#pragma unroll
        for (int kt = 0; kt < 2; ++kt)
#pragma unroll
            for (int j = 0; j < 8; ++j) {
                const int unit = 32 * kt + 16 * (j >> 2) + 4 * u + (j & 3);
                w2f[dt][kt][j] = f2bf(W2[unit * 64 + 16 * dt + p]);
            }

    float b2r[4][4];
#pragma unroll
    for (int dt = 0; dt < 4; ++dt)
#pragma unroll
        for (int r = 0; r < 4; ++r)
            b2r[dt][r] = b2[16 * dt + 4 * u + r];

    const short one_bf = f2bf(1.0f);
    const int NG = 65536, S = 3072;

    // ---- software-pipeline prologue ----
    const int g0 = wid;
    const int row0 = g0 * 16 + p;
    int   nb0 = idx[row0];
    float dC  = dist[row0];
    const float* cp0 = xyz + (size_t)g0 * 3;
    float cC0 = cp0[0], cC1 = cp0[1], cC2 = cp0[2];
    const float* np0 = xyz + ((size_t)((g0 >> 12) * 4096) + nb0) * 3;
    float nC0 = np0[0], nC1 = np0[1], nC2 = np0[2];
    int g1 = g0 + S; if (g1 >= NG) g1 = g0;
    const int row1 = g1 * 16 + p;
    int   nbN = idx[row1];
    float dN  = dist[row1];

    for (int g = g0; g < NG; g += S) {
        int gB = g + S;     if (gB >= NG) gB = g;   // t+1 (clamped dummy)
        int gA = g + 2 * S; if (gA >= NG) gA = g;   // t+2 (clamped dummy)

        // ---- 1. issue xyz loads for t+1 (neighbor addr from resident nbN) ----
        const float* cpn = xyz + (size_t)gB * 3;
        float cL0 = cpn[0], cL1 = cpn[1], cL2 = cpn[2];
        const float* npn = xyz + ((size_t)((gB >> 12) * 4096) + nbN) * 3;
        float nL0 = npn[0], nL1 = npn[1], nL2 = npn[2];

        // ---- 2. issue idx/dist loads for t+2 ----
        const int rowA = gA * 16 + p;
        int   nbL = idx[rowA];
        float dL  = dist[rowA];

        // ---- 3. layer-1 MFMA ----
        bf16x8 fa;
        fa[0] = f2bf(cC0); fa[1] = f2bf(cC1); fa[2] = f2bf(cC2);
        fa[3] = f2bf(nC0); fa[4] = f2bf(nC1); fa[5] = f2bf(nC2);
        fa[6] = f2bf(dC);  fa[7] = one_bf;

        f32x4 acc1[4];
#pragma unroll
        for (int t = 0; t < 4; ++t) {
            acc1[t] = (f32x4){0.f, 0.f, 0.f, 0.f};
            acc1[t] = __builtin_amdgcn_mfma_f32_16x16x32_bf16(w1f[t], fa, acc1[t], 0, 0, 0);
            acc1[t][0] = fmaxf(acc1[t][0], 0.f);
            acc1[t][1] = fmaxf(acc1[t][1], 0.f);
            acc1[t][2] = fmaxf(acc1[t][2], 0.f);
            acc1[t][3] = fmaxf(acc1[t][3], 0.f);
        }

        // ---- 4. layer-2 B-frag directly from acc1 (permutation-matched) ----
        bf16x8 hb[2];
#pragma unroll
        for (int kt = 0; kt < 2; ++kt)
#pragma unroll
            for (int j = 0; j < 8; ++j)
                hb[kt][j] = f2bf(acc1[2 * kt + (j >> 2)][j & 3]);

        // ---- 5. layer-2 MFMA, bias in C-init: D2[dim][pt] ----
        f32x4 acc2[4];
#pragma unroll
        for (int dt = 0; dt < 4; ++dt) {
            acc2[dt] = (f32x4){b2r[dt][0], b2r[dt][1], b2r[dt][2], b2r[dt][3]};
            acc2[dt] = __builtin_amdgcn_mfma_f32_16x16x32_bf16(w2f[dt][0], hb[0], acc2[dt], 0, 0, 0);
            acc2[dt] = __builtin_amdgcn_mfma_f32_16x16x32_bf16(w2f[dt][1], hb[1], acc2[dt], 0, 0, 0);
        }

        // ---- 6. transpose via LDS (swizzled, conflict-free) ----
#pragma unroll
        for (int dt = 0; dt < 4; ++dt) {
            const int col = (16 * dt + 4 * u) ^ ((p & 1) << 4);
            *(f32x4*)&ws[p * 64 + col] = acc2[dt];
        }

        // ---- 7. LDS -> 4x 1KB contiguous stores; NT/plain striped at 2MB ----
        float* const obase = out + (size_t)g * 1024;
        if ((g >> 9) & 1) {
#pragma unroll
            for (int i = 0; i < 4; ++i) {
                const int pt = 4 * i + u;
                f32x4 v = *(const f32x4*)&ws[pt * 64 + ((4 * p) ^ ((u & 1) << 4))];
                __builtin_nontemporal_store(v, (f32x4*)&obase[i * 256 + lane * 4]);
            }
        } else {
#pragma unroll
            for (int i = 0; i < 4; ++i) {
                const int pt = 4 * i + u;
                f32x4 v = *(const f32x4*)&ws[pt * 64 + ((4 * p) ^ ((u & 1) << 4))];
                *(f32x4*)&obase[i * 256 + lane * 4] = v;
            }
        }

        // ---- 8. rotate pipeline registers ----
        cC0 = cL0; cC1 = cL1; cC2 = cL2;
        nC0 = nL0; nC1 = nL1; nC2 = nL2;
        dC  = dN;  dN  = dL;  nbN = nbL;
    }
}

extern "C" void kernel_launch(void* const* d_in, const int* in_sizes, int n_in,
                              void* d_out, int out_size, void* d_ws, size_t ws_size,
                              hipStream_t stream) {
    const float* xyz  = (const float*)d_in[0];
    const float* dist = (const float*)d_in[1];
    const float* W1   = (const float*)d_in[2];
    const float* b1   = (const float*)d_in[3];
    const float* W2   = (const float*)d_in[4];
    const float* b2   = (const float*)d_in[5];
    const int*   idx  = (const int*)d_in[6];
    float* out = (float*)d_out;

    ppe_kernel<<<dim3(768), dim3(256), 0, stream>>>(xyz, dist, W1, b1, W2, b2, idx, out);
}